// Round 6
// baseline (142.188 us; speedup 1.0000x reference)
//
#include <hip/hip_runtime.h>
#include <math.h>

// Problem constants (from reference)
#define INPUT_DIM 30000
#define UNITS     2048
#define NNZ       500000
#define BATCH     32

// ---------------------------------------------------------------------------
// R10: R8 structure (proven 78.5 us) minus one launch. R9 post-mortem:
// grid-wide fusion is dead on gfx950 (cg: ~50us/barrier; manual spin: fence
// + cross-XCD coherence cost ~39MB write amplification, net -4.6us). The
// surviving levers were launch-count and in-kernel concurrency, so:
//  - transpose_k: unchanged from R8 (zeroing rides along, 938 WGs).
//  - scatter_k: unchanged gather core (octet/128B mapping, XCD swizzle,
//    32 waves/CU) + guard folded into a last-WG ticket tail: clean path
//    costs one threadfence + one atomicAdd + syncthreads per WG; dirty
//    path (spill/collision, never for this data) rewrites out from
//    ws2+spill with atomic loads. Launches: 3 -> 2.
// ---------------------------------------------------------------------------

// Kernel 1: transpose x [32][30000] -> xt [30000][32] + zero ws2/spill/claim/
// flag/done (33281 float4 covers 65536+65536 f + 2048 claim + flag/done).
__global__ __launch_bounds__(256) void transpose_k(const float* __restrict__ x,
                                                   float* __restrict__ xt,
                                                   float4* __restrict__ zero4) {
    {
        int g = blockIdx.x * 256 + threadIdx.x;
        if (g < 33281) zero4[g] = make_float4(0.f, 0.f, 0.f, 0.f);
    }
    __shared__ float tile[32][33];                // +1 pad
    const int i0 = blockIdx.x * 32;
    const int t  = threadIdx.x;
    const int l  = t & 31;                        // col within tile
    #pragma unroll
    for (int rep = 0; rep < 4; ++rep) {           // 4 batch rows per thread
        int b = rep * 8 + (t >> 5);
        if (i0 + l < INPUT_DIM)
            tile[b][l] = x[b * INPUT_DIM + i0 + l];
        else
            tile[b][l] = 0.f;
    }
    __syncthreads();
    const int il = t >> 3;                        // 0..31
    const int b4 = t & 7;                         // batch quad 0..7
    if (i0 + il < INPUT_DIM)
        ((float4*)xt)[(size_t)(i0 + il) * 8 + b4] =
            make_float4(tile[b4 * 4 + 0][il], tile[b4 * 4 + 1][il],
                        tile[b4 * 4 + 2][il], tile[b4 * 4 + 3][il]);
}

// ---------------------------------------------------------------------------
// Kernel 2: residue-per-WG scatter, register accumulation, fused epilogue,
// last-WG guard tail. Thread = (bg 0..7 fastest, es 0..63); 4 entries/thread.
// Grid 2048 x 512; launch_bounds(512,8) -> 64 VGPR cap, 32 waves/CU.
// ---------------------------------------------------------------------------
__global__ __launch_bounds__(512, 8) void scatter_k(const int* __restrict__ idx,
                                                    const float* __restrict__ kv,
                                                    const float* __restrict__ xt,
                                                    float* __restrict__ ws2,
                                                    float* __restrict__ spill,
                                                    const float* __restrict__ bias,
                                                    float* __restrict__ out,
                                                    int* __restrict__ claim,
                                                    int* __restrict__ flag,
                                                    int* __restrict__ done) {
    __shared__ float part[64 * 32];               // [es][b]  8 KB
    __shared__ int   lastDirty;

    const int t    = threadIdx.x;
    const int bg   = t & 7;                       // octet covers one 128B row
    const int es   = t >> 3;                      // 0..63
    // XCD-chunk swizzle: XCD (bid&7) owns residues [(bid&7)*256, +256) so
    // consecutive residues (same idx/kv cache lines) share one L2.
    const int r    = ((blockIdx.x & 7) << 8) + (blockIdx.x >> 3);  // 0..2047
    const int boff = bg * 4;

    // int64 vs int32 index detection (uniform): int64 LE -> high words zero.
    const bool is64 = ((idx[3] | idx[5] | idx[7]) == 0);
    const int  col0 = is64 ? idx[4 * r + 2] : idx[2 * r + 1];  // WG-uniform

    // claim: detect col0 collisions across residues (check deferred to end)
    int claimOld = 0;
    if (t == 0) { lastDirty = 0; claimOld = atomicAdd(&claim[col0], 1); }

    // ---- all 4 idx/kv loads issued together (octet lanes same addr) ----
    const int base = r + UNITS * es;              // m = es + 64*j stripes
    int   rows[4], cols[4];
    float vals[4];
    if (is64) {
        const int4* __restrict__ p = (const int4*)idx;
        #pragma unroll
        for (int j = 0; j < 4; ++j) {
            int  e  = base + j * (UNITS * 64);    // +131072 entries
            bool ok = e < NNZ;
            int4 q  = ok ? p[e] : make_int4(0, 0, col0, 0);
            rows[j] = q.x; cols[j] = q.z;
            vals[j] = ok ? kv[e] : 0.f;
        }
    } else {
        const int2* __restrict__ p = (const int2*)idx;
        #pragma unroll
        for (int j = 0; j < 4; ++j) {
            int  e  = base + j * (UNITS * 64);
            bool ok = e < NNZ;
            int2 q  = ok ? p[e] : make_int2(0, col0);
            rows[j] = q.x; cols[j] = q.y;
            vals[j] = ok ? kv[e] : 0.f;
        }
    }

    // ---- 4 gathers in flight (16B/lane; octet jointly covers 128B row) ----
    float4 g[4];
    #pragma unroll
    for (int j = 0; j < 4; ++j)
        g[j] = *(const float4*)(xt + rows[j] * 32 + boff);
    __builtin_amdgcn_sched_barrier(0);            // keep gathers issued first

    float acc[4] = {0.f, 0.f, 0.f, 0.f};
    #pragma unroll
    for (int j = 0; j < 4; ++j) {
        float v = vals[j];
        if (cols[j] == col0) {                    // uniformly true for this data
            acc[0] += v * g[j].x; acc[1] += v * g[j].y;
            acc[2] += v * g[j].z; acc[3] += v * g[j].w;
        } else {                                  // correctness fallback
            atomicAdd(flag, 1);
            float* __restrict__ sp = spill + cols[j];
            atomicAdd(sp + (boff + 0) * UNITS, v * g[j].x);
            atomicAdd(sp + (boff + 1) * UNITS, v * g[j].y);
            atomicAdd(sp + (boff + 2) * UNITS, v * g[j].z);
            atomicAdd(sp + (boff + 3) * UNITS, v * g[j].w);
        }
    }

    // combine 64 es-stripes via LDS
    #pragma unroll
    for (int bb = 0; bb < 4; ++bb)
        part[es * 32 + boff + bb] = acc[bb];
    if (claimOld != 0) atomicAdd(flag, 1);        // deferred collision check
    __syncthreads();

    if (t < 32) {
        const int b = t;                          // batch row
        float s = 0.f;
        #pragma unroll
        for (int e = 0; e < 64; ++e) s += part[e * 32 + b];
        // ws2 keeps the full sum for the guard path (collisions accumulate)
        atomicAdd(&ws2[b * UNITS + col0], s);
        // fused epilogue: valid whenever no spill and no collision anywhere
        out[b * UNITS + col0] = tanhf(s + bias[col0]);
    }

    // ---- last-WG guard tail (replaces guard_k launch) ----
    __syncthreads();                              // epilogue stores issued
    if (t == 0) {
        __threadfence();                          // release our out/ws2 writes
        if (atomicAdd(done, 1) == (int)gridDim.x - 1) {
            // last WG system-wide: all other WGs' atomics/writes are visible
            if (__hip_atomic_load(flag, __ATOMIC_ACQUIRE,
                                  __HIP_MEMORY_SCOPE_AGENT) != 0)
                lastDirty = 1;
        }
    }
    __syncthreads();
    if (lastDirty) {                              // correctness-only path
        for (int i = t; i < BATCH * UNITS; i += 512) {
            int c = i & (UNITS - 1);
            float w = __hip_atomic_load(&ws2[i], __ATOMIC_RELAXED,
                                        __HIP_MEMORY_SCOPE_AGENT);
            float s = __hip_atomic_load(&spill[i], __ATOMIC_RELAXED,
                                        __HIP_MEMORY_SCOPE_AGENT);
            out[i] = tanhf(w + s + bias[c]);
        }
    }
}

// ---------------------------------------------------------------------------
extern "C" void kernel_launch(void* const* d_in, const int* in_sizes, int n_in,
                              void* d_out, int out_size, void* d_ws, size_t ws_size,
                              hipStream_t stream) {
    const float* x    = (const float*)d_in[0];
    const float* kv   = (const float*)d_in[1];
    const float* bias = (const float*)d_in[2];
    const int*   idx  = (const int*)d_in[3];
    float*       out  = (float*)d_out;

    // workspace: xt [960000 f] | ws2 [65536 f] | spill [65536 f] |
    //            claim [2048 i] | flag [1 i] | done [1 i]
    float* xt    = (float*)d_ws;
    float* ws2   = xt + (size_t)INPUT_DIM * BATCH;
    float* spill = ws2 + BATCH * UNITS;
    int*   claim = (int*)(spill + BATCH * UNITS);
    int*   flag  = claim + UNITS;
    int*   done  = flag + 1;

    transpose_k<<<(INPUT_DIM + 31) / 32, 256, 0, stream>>>(x, xt, (float4*)ws2);
    scatter_k<<<UNITS, 512, 0, stream>>>(idx, kv, xt, ws2, spill, bias, out,
                                         claim, flag, done);
}

// Round 7
// 78.816 us; speedup vs baseline: 1.8041x; 1.8041x over previous
//
#include <hip/hip_runtime.h>
#include <math.h>

// Problem constants (from reference)
#define INPUT_DIM 30000
#define UNITS     2048
#define NNZ       500000
#define BATCH     32

// ---------------------------------------------------------------------------
// R11: exact revert to R8 (measured 78.5 us). R10's last-WG guard tail
// (threadfence + done-ticket) serialized scatter_k to 80 us AND collapsed
// its VGPR allocation to 24 (serialized gathers). Lesson logged: device-
// scope fences on gfx950 are ruinous (3rd independent confirmation), and
// tail code perturbs hot-body codegen. This file is byte-identical to the
// R8 submission.
//  - transpose_k: 32-col tiles, 938 WGs (~15 waves/CU), zeroing rides along.
//  - scatter_k: 1 residue/WG, octet mapping (8 lanes x 16B = one 128B xt
//    row), XCD-chunk swizzle, launch_bounds(512,8) -> 32 waves/CU.
//  - guard_k: early-exits on one scalar read when clean (launch cost only).
// Correctness for arbitrary indices: spill path + claim collision detection.
// ---------------------------------------------------------------------------

// Kernel 1: transpose x [32][30000] -> xt [30000][32] + zero ws2/spill/claim/flag.
__global__ __launch_bounds__(256) void transpose_k(const float* __restrict__ x,
                                                   float* __restrict__ xt,
                                                   float4* __restrict__ zero4) {
    // zero ws2 (65536 f) + spill (65536 f) + claim (2048 i) + flag: 33281 float4
    {
        int g = blockIdx.x * 256 + threadIdx.x;
        if (g < 33281) zero4[g] = make_float4(0.f, 0.f, 0.f, 0.f);
    }
    __shared__ float tile[32][33];                // +1 pad
    const int i0 = blockIdx.x * 32;
    const int t  = threadIdx.x;
    const int l  = t & 31;                        // col within tile
    #pragma unroll
    for (int rep = 0; rep < 4; ++rep) {           // 4 batch rows per thread
        int b = rep * 8 + (t >> 5);
        if (i0 + l < INPUT_DIM)
            tile[b][l] = x[b * INPUT_DIM + i0 + l];
        else
            tile[b][l] = 0.f;
    }
    __syncthreads();
    const int il = t >> 3;                        // 0..31
    const int b4 = t & 7;                         // batch quad 0..7
    if (i0 + il < INPUT_DIM)
        ((float4*)xt)[(size_t)(i0 + il) * 8 + b4] =
            make_float4(tile[b4 * 4 + 0][il], tile[b4 * 4 + 1][il],
                        tile[b4 * 4 + 2][il], tile[b4 * 4 + 3][il]);
}

// ---------------------------------------------------------------------------
// Kernel 2: residue-per-WG scatter, register accumulation, fused epilogue.
// Thread = (bg 0..7 fastest, es 0..63); 4 entries/thread (m = es + 64*j).
// Grid 2048 x 512; launch_bounds(512,8) -> 64 VGPR cap, 32 waves/CU.
// ---------------------------------------------------------------------------
__global__ __launch_bounds__(512, 8) void scatter_k(const int* __restrict__ idx,
                                                    const float* __restrict__ kv,
                                                    const float* __restrict__ xt,
                                                    float* __restrict__ ws2,
                                                    float* __restrict__ spill,
                                                    const float* __restrict__ bias,
                                                    float* __restrict__ out,
                                                    int* __restrict__ claim,
                                                    int* __restrict__ flag) {
    __shared__ float part[64 * 32];               // [es][b]  8 KB

    const int t    = threadIdx.x;
    const int bg   = t & 7;                       // octet covers one 128B row
    const int es   = t >> 3;                      // 0..63
    // XCD-chunk swizzle: XCD (bid&7) owns residues [ (bid&7)*256, +256 ) so
    // consecutive residues (same idx/kv cache lines) share one L2.
    const int r    = ((blockIdx.x & 7) << 8) + (blockIdx.x >> 3);  // 0..2047
    const int boff = bg * 4;

    // int64 vs int32 index detection (uniform): int64 LE -> high words zero.
    const bool is64 = ((idx[3] | idx[5] | idx[7]) == 0);
    const int  col0 = is64 ? idx[4 * r + 2] : idx[2 * r + 1];  // WG-uniform

    // claim: detect col0 collisions across residues (check deferred to end)
    int claimOld = 0;
    if (t == 0) claimOld = atomicAdd(&claim[col0], 1);

    // ---- all 4 idx/kv loads issued together (octet lanes same addr) ----
    const int base = r + UNITS * es;              // m = es + 64*j stripes
    int   rows[4], cols[4];
    float vals[4];
    if (is64) {
        const int4* __restrict__ p = (const int4*)idx;
        #pragma unroll
        for (int j = 0; j < 4; ++j) {
            int  e  = base + j * (UNITS * 64);    // +131072 entries
            bool ok = e < NNZ;
            int4 q  = ok ? p[e] : make_int4(0, 0, col0, 0);
            rows[j] = q.x; cols[j] = q.z;
            vals[j] = ok ? kv[e] : 0.f;
        }
    } else {
        const int2* __restrict__ p = (const int2*)idx;
        #pragma unroll
        for (int j = 0; j < 4; ++j) {
            int  e  = base + j * (UNITS * 64);
            bool ok = e < NNZ;
            int2 q  = ok ? p[e] : make_int2(0, col0);
            rows[j] = q.x; cols[j] = q.y;
            vals[j] = ok ? kv[e] : 0.f;
        }
    }

    // ---- 4 gathers in flight (16B/lane; octet jointly covers 128B row) ----
    float4 g[4];
    #pragma unroll
    for (int j = 0; j < 4; ++j)
        g[j] = *(const float4*)(xt + rows[j] * 32 + boff);
    __builtin_amdgcn_sched_barrier(0);            // keep gathers issued first

    float acc[4] = {0.f, 0.f, 0.f, 0.f};
    #pragma unroll
    for (int j = 0; j < 4; ++j) {
        float v = vals[j];
        if (cols[j] == col0) {                    // uniformly true for this data
            acc[0] += v * g[j].x; acc[1] += v * g[j].y;
            acc[2] += v * g[j].z; acc[3] += v * g[j].w;
        } else {                                  // correctness fallback
            atomicAdd(flag, 1);
            float* __restrict__ sp = spill + cols[j];
            atomicAdd(sp + (boff + 0) * UNITS, v * g[j].x);
            atomicAdd(sp + (boff + 1) * UNITS, v * g[j].y);
            atomicAdd(sp + (boff + 2) * UNITS, v * g[j].z);
            atomicAdd(sp + (boff + 3) * UNITS, v * g[j].w);
        }
    }

    // combine 64 es-stripes via LDS
    #pragma unroll
    for (int bb = 0; bb < 4; ++bb)
        part[es * 32 + boff + bb] = acc[bb];
    if (claimOld != 0) atomicAdd(flag, 1);        // deferred collision check
    __syncthreads();

    if (t < 32) {
        const int b = t;                          // batch row
        float s = 0.f;
        #pragma unroll
        for (int e = 0; e < 64; ++e) s += part[e * 32 + b];
        // ws2 keeps the full sum for the guard path (collisions accumulate)
        atomicAdd(&ws2[b * UNITS + col0], s);
        // fused epilogue: valid whenever no spill and no collision anywhere
        out[b * UNITS + col0] = tanhf(s + bias[col0]);
    }
}

// ---------------------------------------------------------------------------
// Kernel 3: guard — early-exits on one scalar read when the fused epilogue
// was valid (flag == 0); otherwise recomputes out = tanh(ws2 + spill + bias).
// ---------------------------------------------------------------------------
__global__ __launch_bounds__(256) void guard_k(const float* __restrict__ ws2,
                                               const float* __restrict__ spill,
                                               const float* __restrict__ bias,
                                               const int* __restrict__ flag,
                                               float* __restrict__ out) {
    if (__builtin_expect(*flag == 0, 1)) return;  // clean: launch-cost only
    int tid = blockIdx.x * 256 + threadIdx.x;     // 0..65535
    int c   = tid & (UNITS - 1);
    out[tid] = tanhf(ws2[tid] + spill[tid] + bias[c]);
}

// ---------------------------------------------------------------------------
extern "C" void kernel_launch(void* const* d_in, const int* in_sizes, int n_in,
                              void* d_out, int out_size, void* d_ws, size_t ws_size,
                              hipStream_t stream) {
    const float* x    = (const float*)d_in[0];
    const float* kv   = (const float*)d_in[1];
    const float* bias = (const float*)d_in[2];
    const int*   idx  = (const int*)d_in[3];
    float*       out  = (float*)d_out;

    // workspace: xt [960000 f] | ws2 [65536 f] | spill [65536 f] | claim [2048 i] | flag [1 i]
    float* xt    = (float*)d_ws;
    float* ws2   = xt + (size_t)INPUT_DIM * BATCH;
    float* spill = ws2 + BATCH * UNITS;
    int*   claim = (int*)(spill + BATCH * UNITS);
    int*   flag  = claim + UNITS;

    transpose_k<<<(INPUT_DIM + 31) / 32, 256, 0, stream>>>(x, xt, (float4*)ws2);
    scatter_k<<<UNITS, 512, 0, stream>>>(idx, kv, xt, ws2, spill, bias, out,
                                         claim, flag);
    guard_k<<<(BATCH * UNITS) / 256, 256, 0, stream>>>(ws2, spill, bias, flag, out);
}